// Round 2
// baseline (272.449 us; speedup 1.0000x reference)
//
#include <hip/hip_runtime.h>

static constexpr int B_    = 64;
static constexpr int N_    = 2048;
static constexpr int DI_   = 8;
static constexpr int O_    = 32;
static constexpr int P_    = 16;
static constexpr int OP_   = O_ * P_;      // 512
static constexpr int M_    = OP_ * B_;     // 32768 s elements
static constexpr int CHUNK_ = 8;
static constexpr int NBLK_  = N_ / CHUNK_; // 256
static constexpr int WSLICE_ = O_ * P_ * DI_;  // 4096 floats per n

// async global->LDS, 16B per lane; LDS dest wave-uniform, HW writes dest+lane*16.
__device__ __forceinline__ void stage_w16(const float* g, float* l) {
  __builtin_amdgcn_global_load_lds(
      (const __attribute__((address_space(1))) void*)g,
      (__attribute__((address_space(3))) void*)l,
      16, 0, 0);
}

// DPP add helper: v + dpp_mov(v). CTRL compile-time (0xB1 quad_perm[1,0,3,2];
// 0x121/2/4/8 = row_ror 1/2/4/8).
template <int CTRL>
__device__ __forceinline__ float dpp_add(float v) {
  int t = __builtin_amdgcn_update_dpp(0, __float_as_int(v), CTRL, 0xf, 0xf, false);
  return v + __int_as_float(t);
}

__device__ __forceinline__ float rfl(float v) {
  return __int_as_float(__builtin_amdgcn_readfirstlane(__float_as_int(v)));
}

// R2 remap: lane = (o = lane>>1, ph = lane&1); wave owns b-quad {4w..4w+3}.
//  - W: per-lane distinct ds_read_b128 x16/nn (was 64 broadcast) via XOR swizzle
//    pc = lc ^ ((lc>>5)&7) applied to the *global source* of global_load_lds
//    (LDS dest must stay linear) and to the read address. 8/slot even spread.
//  - x: wave-uniform -> read 8 b128/nn, values moved to SGPRs via readfirstlane
//    (scalar FMA operand, zero VGPR cost).
//  - softmax fully in-wave (wave spans all 32 o): DPP quad_perm ph-pair add,
//    DPP row_ror rotate-reduce over 16, __shfl_xor for 16/32. z_lds gone.
//  - cross-wave W consumption => per-nn: vmcnt(0); barrier; issue stage(nn+1).
//    Prefetch overlaps one full compute iteration.
//  - s_out layout now [blk][b][q] (coalesced epilogue); v_kernel re-indexed.
template <int MODE, bool ATOMIC>
__global__ __launch_bounds__(1024, 4)
void fused_pass(const float* __restrict__ x, const float* __restrict__ W,
                const float* __restrict__ v_in, float* __restrict__ s_out,
                float* __restrict__ rw_out) {
  __shared__ __align__(16) float w_lds[2][WSLICE_];   // 32 KB dbuf W slice
  __shared__ __align__(16) float x_lds[CHUNK_ * 512]; // [nn][b][i] 16 KB
  const int tid  = threadIdx.x;
  const int lane = tid & 63;
  const int wave = tid >> 6;
  const int wu   = __builtin_amdgcn_readfirstlane(wave);
  const int o    = lane >> 1;   // 0..31 output capsule
  const int ph   = lane & 1;    // p-half: p = ph*8 + pp
  const int q3   = o & 7;       // read-swizzle key
  const int n0   = blockIdx.x * CHUNK_;

  // ---- stage x -> LDS [nn][b][i]: coalesced global float4, b128 LDS write
  {
    const int bs = tid >> 4;    // b
    const int cs = tid & 15;    // 16B chunk: nn = cs>>1, ih = cs&1
    const float4 xv =
        *(const float4*)(x + (size_t)bs * (N_ * DI_) + n0 * DI_ + cs * 4);
    *(float4*)&x_lds[(cs >> 1) * 512 + bs * 8 + (cs & 1) * 4] = xv;
  }

  // ---- hoist v fragments (nn-invariant): vv[bb][pp], p = ph*8+pp
  float vv[4][8];
  if (MODE != 0) {
    #pragma unroll
    for (int bb = 0; bb < 4; ++bb) {
      const float4* vp = (const float4*)(v_in + (size_t)(wu * 4 + bb) * OP_ +
                                         o * P_ + ph * 8);
      const float4 a = vp[0], c = vp[1];
      vv[bb][0] = a.x; vv[bb][1] = a.y; vv[bb][2] = a.z; vv[bb][3] = a.w;
      vv[bb][4] = c.x; vv[bb][5] = c.y; vv[bb][6] = c.z; vv[bb][7] = c.w;
    }
  }

  float s_r[4][8];
  #pragma unroll
  for (int bb = 0; bb < 4; ++bb)
    #pragma unroll
    for (int pp = 0; pp < 8; ++pp) s_r[bb][pp] = 0.0f;

  // swizzled stage source chunk: LDS physical chunk tid holds global chunk
  // sg = tid ^ ((tid>>5)&7)  (involution; read side inverts it).
  const int sg = tid ^ ((tid >> 5) & 7);

  // stage W[n0] into buf0
  stage_w16(W + (size_t)n0 * WSLICE_ + (size_t)sg * 4, &w_lds[0][wu * 256]);

  #pragma unroll 1
  for (int nn = 0; nn < CHUNK_; ++nn) {
    // own stage(nn) done -> all waves' stage(nn) done after barrier; barrier
    // also guarantees all reads of buf[(nn+1)&1] (iter nn-1) completed, so
    // issuing stage(nn+1) after it is WAW-safe.
    asm volatile("s_waitcnt vmcnt(0)" ::: "memory");
    __syncthreads();
    if (nn + 1 < CHUNK_)
      stage_w16(W + (size_t)(n0 + nn + 1) * WSLICE_ + (size_t)sg * 4,
                &w_lds[(nn + 1) & 1][wu * 256]);

    // x -> SGPR (wave-uniform): 8 broadcast b128 reads, readfirstlane each
    float xs[4][8];
    #pragma unroll
    for (int bb = 0; bb < 4; ++bb) {
      const float4 xa = *(const float4*)&x_lds[nn * 512 + (wu * 4 + bb) * 8];
      const float4 xc = *(const float4*)&x_lds[nn * 512 + (wu * 4 + bb) * 8 + 4];
      xs[bb][0] = rfl(xa.x); xs[bb][1] = rfl(xa.y);
      xs[bb][2] = rfl(xa.z); xs[bb][3] = rfl(xa.w);
      xs[bb][4] = rfl(xc.x); xs[bb][5] = rfl(xc.y);
      xs[bb][6] = rfl(xc.z); xs[bb][7] = rfl(xc.w);
    }

    float pr[4][8];
    float acc[4] = {0.0f, 0.0f, 0.0f, 0.0f};
    const int wbase = ((nn & 1) ? WSLICE_ : 0) + o * 128 + ph * 64;

    #pragma unroll
    for (int pp = 0; pp < 8; ++pp) {
      const int c0 = (2 * pp) ^ q3;          // swizzled 16B chunk idx
      const int c1 = (2 * pp + 1) ^ q3;
      const float4 w0 = *(const float4*)&w_lds[0][wbase + c0 * 4];
      const float4 w1 = *(const float4*)&w_lds[0][wbase + c1 * 4];
      #pragma unroll
      for (int bb = 0; bb < 4; ++bb) {
        float pv = w0.x * xs[bb][0];
        pv = __builtin_fmaf(w0.y, xs[bb][1], pv);
        pv = __builtin_fmaf(w0.z, xs[bb][2], pv);
        pv = __builtin_fmaf(w0.w, xs[bb][3], pv);
        pv = __builtin_fmaf(w1.x, xs[bb][4], pv);
        pv = __builtin_fmaf(w1.y, xs[bb][5], pv);
        pv = __builtin_fmaf(w1.z, xs[bb][6], pv);
        pv = __builtin_fmaf(w1.w, xs[bb][7], pv);
        if (MODE == 0) {
          s_r[bb][pp] += pv;
        } else {
          pr[bb][pp] = pv;
          acc[bb] = __builtin_fmaf(pv, vv[bb][pp], acc[bb]);
        }
      }
    }

    if (MODE != 0) {
      #pragma unroll
      for (int bb = 0; bb < 4; ++bb) {
        // full logit = both p-halves (quad_perm xor1 pairs lanes 2o/2o+1)
        const float full = dpp_add<0xB1>(acc[bb]);
        const float e = __expf(full);
        // sum over all 64 lanes = 2*Z[b] (each o counted twice via ph)
        float srow = e;
        srow = dpp_add<0x121>(srow);
        srow = dpp_add<0x122>(srow);
        srow = dpp_add<0x124>(srow);
        srow = dpp_add<0x128>(srow);
        float t2 = srow + __shfl_xor(srow, 16);
        const float S = t2 + __shfl_xor(t2, 32);   // = 2*Z
        const float rw = (2.0f * e) / S;           // e/Z
        #pragma unroll
        for (int pp = 0; pp < 8; ++pp)
          s_r[bb][pp] = __builtin_fmaf(rw, pr[bb][pp], s_r[bb][pp]);
        if (MODE == 2) {
          if (ph == 0)
            rw_out[((size_t)(wu * 4 + bb) * N_ + (n0 + nn)) * O_ + o] = rw;
        }
      }
    }
  }

  // epilogue, s layout [b][q=o*16+p]: contiguous 2KB per store instr
  if (ATOMIC) {
    #pragma unroll
    for (int bb = 0; bb < 4; ++bb) {
      float* sp = s_out + (size_t)(wu * 4 + bb) * OP_ + o * P_ + ph * 8;
      #pragma unroll
      for (int pp = 0; pp < 8; ++pp) atomicAdd(&sp[pp], s_r[bb][pp]);
    }
  } else {
    #pragma unroll
    for (int bb = 0; bb < 4; ++bb) {
      float* sp = s_out + (size_t)blockIdx.x * M_ +
                  (size_t)(wu * 4 + bb) * OP_ + o * P_ + ph * 8;
      float4 st0, st1;
      st0.x = s_r[bb][0]; st0.y = s_r[bb][1]; st0.z = s_r[bb][2]; st0.w = s_r[bb][3];
      st1.x = s_r[bb][4]; st1.y = s_r[bb][5]; st1.z = s_r[bb][6]; st1.w = s_r[bb][7];
      *(float4*)sp = st0;
      *(float4*)(sp + 4) = st1;
    }
  }
}

// stage-1 reduction: P[K][M_] -> P2[16][M_]; grid 16 groups x 16 m-chunks.
// (element-wise over flat M_, layout-agnostic)
__global__ __launch_bounds__(1024)
void reduce1(const float* __restrict__ spart, float* __restrict__ p2, int K) {
  const int g  = blockIdx.x >> 4;
  const int mc = blockIdx.x & 15;
  const int kpg = K >> 4;
  const int m0 = mc * 2048 + threadIdx.x;
  float a0 = 0.0f, a1 = 0.0f;
  const float* p = spart + (size_t)(g * kpg) * M_;
  for (int k = 0; k < kpg; ++k) {
    a0 += p[(size_t)k * M_ + m0];
    a1 += p[(size_t)k * M_ + m0 + 1024];
  }
  p2[(size_t)g * M_ + m0]        = a0;
  p2[(size_t)g * M_ + m0 + 1024] = a1;
}

// sum ngroups (stride M_, layout [b][q]) + squash; optional v_add / zero_buf.
__global__ __launch_bounds__(1024)
void v_kernel(const float* __restrict__ src, int ngroups, float scale,
              const float* __restrict__ v_add, float* __restrict__ v_out,
              float* __restrict__ zero_buf) {
  __shared__ float sq[P_ * 65];
  const int t = threadIdx.x;
  const int p = t & 15;
  const int b = t >> 4;
  const int o = blockIdx.x;
  const int q = o * P_ + p;
  float acc = 0.0f;
  for (int g = 0; g < ngroups; ++g)
    acc += src[(size_t)g * M_ + (size_t)b * OP_ + q];
  acc *= scale;
  sq[p * 65 + b] = acc * acc;
  if (zero_buf) zero_buf[blockIdx.x * 1024 + t] = 0.0f;
  __syncthreads();
  float s2 = 0.0f;
  #pragma unroll
  for (int pp = 0; pp < P_; ++pp) s2 += sq[pp * 65 + b];
  float sc = (s2 / (1.0f + s2)) / sqrtf(s2 + 1e-7f);
  float v = acc * sc;
  const int idx = b * OP_ + q;   // v layout [b][o][p]
  v_out[idx] = v + (v_add ? v_add[idx] : 0.0f);
}

extern "C" void kernel_launch(void* const* d_in, const int* in_sizes, int n_in,
                              void* d_out, int out_size, void* d_ws, size_t ws_size,
                              hipStream_t stream) {
  (void)in_sizes; (void)n_in; (void)out_size;
  const float* x = (const float*)d_in[0];
  const float* W = (const float*)d_in[1];
  float* out_v  = (float*)d_out;                       // [64][32][16]
  float* out_rw = out_v + (size_t)B_ * O_ * P_;        // [64][2048][32]
  float* vws   = (float*)d_ws;                         // v0
  float* vsum  = vws + M_;                             // v0+v1
  float* p2    = vsum + M_;                            // 16 * M_
  float* spart = p2 + 16 * M_;                         // NBLK_ * M_

  const size_t need = (size_t)(2 * M_ + 16 * M_ + (size_t)NBLK_ * M_) * 4;

  dim3 gF(NBLK_), bF(1024), gV(O_), bV(1024), gR(256);
  if (ws_size >= need) {
    fused_pass<0, false><<<gF, bF, 0, stream>>>(x, W, nullptr, spart, nullptr);
    reduce1<<<gR, bF, 0, stream>>>(spart, p2, NBLK_);
    v_kernel<<<gV, bV, 0, stream>>>(p2, 16, 1.0f / 32.0f, nullptr, vws, nullptr);
    fused_pass<1, false><<<gF, bF, 0, stream>>>(x, W, vws, spart, nullptr);
    reduce1<<<gR, bF, 0, stream>>>(spart, p2, NBLK_);
    v_kernel<<<gV, bV, 0, stream>>>(p2, 16, 1.0f, vws, vsum, nullptr);
    fused_pass<2, false><<<gF, bF, 0, stream>>>(x, W, vsum, spart, out_rw);
    reduce1<<<gR, bF, 0, stream>>>(spart, p2, NBLK_);
    v_kernel<<<gV, bV, 0, stream>>>(p2, 16, 1.0f, nullptr, out_v, nullptr);
  } else {
    // atomic fallback for small ws
    float* sAb = p2;
    float* sBb = sAb + M_;
    hipMemsetAsync(sAb, 0, (size_t)M_ * sizeof(float), stream);
    fused_pass<0, true><<<gF, bF, 0, stream>>>(x, W, nullptr, sAb, nullptr);
    v_kernel<<<gV, bV, 0, stream>>>(sAb, 1, 1.0f / 32.0f, nullptr, vws, sBb);
    fused_pass<1, true><<<gF, bF, 0, stream>>>(x, W, vws, sBb, nullptr);
    v_kernel<<<gV, bV, 0, stream>>>(sBb, 1, 1.0f, vws, vsum, sAb);
    fused_pass<2, true><<<gF, bF, 0, stream>>>(x, W, vsum, sAb, out_rw);
    v_kernel<<<gV, bV, 0, stream>>>(sAb, 1, 1.0f, nullptr, out_v, nullptr);
  }
}

// Round 3
// 271.886 us; speedup vs baseline: 1.0021x; 1.0021x over previous
//
#include <hip/hip_runtime.h>

static constexpr int B_    = 64;
static constexpr int N_    = 2048;
static constexpr int DI_   = 8;
static constexpr int O_    = 32;
static constexpr int P_    = 16;
static constexpr int OP_   = O_ * P_;      // 512
static constexpr int M_    = OP_ * B_;     // 32768 s elements
static constexpr int CHUNK_ = 8;
static constexpr int NBLK_  = N_ / CHUNK_; // 256
static constexpr int WSLICE_ = O_ * P_ * DI_;  // 4096 floats per n

// DPP add helper: v + dpp_mov(v). CTRL compile-time (0xB1 quad_perm[1,0,3,2];
// 0x121/2/4/8 = row_ror 1/2/4/8).
template <int CTRL>
__device__ __forceinline__ float dpp_add(float v) {
  int t = __builtin_amdgcn_update_dpp(0, __float_as_int(v), CTRL, 0xf, 0xf, false);
  return v + __int_as_float(t);
}

__device__ __forceinline__ float rfl(float v) {
  return __int_as_float(__builtin_amdgcn_readfirstlane(__float_as_int(v)));
}

// R3: lane=(o=lane>>1, ph=lane&1), wave owns b-quad {4wu..4wu+3} (R2's remap,
// which cuts LDS->RF broadcast volume 4x vs lane=b) with the three R2 memory
// bugs fixed:
//  - W stage: LINEAR coalesced global_load_dwordx4 (chunk tid) -> register ->
//    ds_write_b128 to swizzled phys chunk tid^((tid>>4)&7). Swizzle is
//    LDS-internal only; global traffic stays coalesced (R2 swizzled the
//    global source of global_load_lds -> 12x fetch amplification).
//    Read: addr = (lane*64 + (lane&7)*4) ^ (8*pp) -- 8 words/bank both sides.
//  - x: no LDS; wave-uniform 2KB/nn read direct from global (scalar/broadcast
//    path), values -> SGPR via readfirstlane (scalar FMA operand).
//  - epilogue: spart layout [blk][b][h][lane][j=4] -> every store instr is
//    base + lane*16B, contiguous 1KB (R2's 32B-stride half-sector stores
//    tripled WRITE_SIZE).
// Single 16KB W buffer; W(nn+1) prefetched into regs at loop top (covered by
// the whole compute phase); 2 barriers/nn around the ds_write.
template <int MODE, bool ATOMIC>
__global__ __launch_bounds__(1024, 4)
void fused_pass(const float* __restrict__ x, const float* __restrict__ W,
                const float* __restrict__ v_in, float* __restrict__ s_out,
                float* __restrict__ rw_out) {
  __shared__ __align__(16) float w_lds[WSLICE_];      // 16 KB, single buffer
  const int tid  = threadIdx.x;
  const int lane = tid & 63;
  const int wave = tid >> 6;
  const int wu   = __builtin_amdgcn_readfirstlane(wave);
  const int o    = lane >> 1;   // 0..31 output capsule
  const int ph   = lane & 1;    // p-half: p = ph*8 + pp
  const int n0   = blockIdx.x * CHUNK_;

  // swizzled LDS write chunk (phys = tid ^ ((tid>>4)&7)), float offset
  const int swoff = (tid ^ ((tid >> 4) & 7)) * 4;
  // swizzled read base (floats): lane*64 + (lane&7)*4; per-chunk addr = wbase ^ (8pp)
  const int wbase = lane * 64 + (lane & 7) * 4;

  // ---- hoist v fragments (nn-invariant): vv[bb][pp], p = ph*8+pp
  float vv[4][8];
  if (MODE != 0) {
    #pragma unroll
    for (int bb = 0; bb < 4; ++bb) {
      const float4* vp = (const float4*)(v_in + (size_t)(wu * 4 + bb) * OP_ +
                                         o * P_ + ph * 8);
      const float4 a = vp[0], c = vp[1];
      vv[bb][0] = a.x; vv[bb][1] = a.y; vv[bb][2] = a.z; vv[bb][3] = a.w;
      vv[bb][4] = c.x; vv[bb][5] = c.y; vv[bb][6] = c.z; vv[bb][7] = c.w;
    }
  }

  float s_r[4][8];
  #pragma unroll
  for (int bb = 0; bb < 4; ++bb)
    #pragma unroll
    for (int pp = 0; pp < 8; ++pp) s_r[bb][pp] = 0.0f;

  // prologue: linear coalesced W[n0] load -> swizzled LDS write
  {
    const float4 w0 = *(const float4*)(W + (size_t)n0 * WSLICE_ + tid * 4);
    *(float4*)&w_lds[swoff] = w0;
  }
  __syncthreads();

  #pragma unroll 1
  for (int nn = 0; nn < CHUNK_; ++nn) {
    const int n = n0 + nn;

    // prefetch W[n+1] into regs (linear, coalesced); consumed after compute.
    float4 wreg;
    if (nn + 1 < CHUNK_)
      wreg = *(const float4*)(W + (size_t)(n + 1) * WSLICE_ + tid * 4);

    // x: wave-uniform 8 floats per b -> scalar regs (2KB/nn total, K$/L2)
    float xs[4][8];
    #pragma unroll
    for (int bb = 0; bb < 4; ++bb) {
      const float* xp = x + (size_t)(wu * 4 + bb) * (N_ * DI_) + (size_t)n * DI_;
      const float4 xa = *(const float4*)xp;
      const float4 xc = *(const float4*)(xp + 4);
      xs[bb][0] = rfl(xa.x); xs[bb][1] = rfl(xa.y);
      xs[bb][2] = rfl(xa.z); xs[bb][3] = rfl(xa.w);
      xs[bb][4] = rfl(xc.x); xs[bb][5] = rfl(xc.y);
      xs[bb][6] = rfl(xc.z); xs[bb][7] = rfl(xc.w);
    }

    float pr[4][8];
    float acc[4] = {0.0f, 0.0f, 0.0f, 0.0f};

    #pragma unroll
    for (int pp = 0; pp < 8; ++pp) {
      const float4 w0 = *(const float4*)&w_lds[wbase ^ (8 * pp)];
      const float4 w1 = *(const float4*)&w_lds[wbase ^ (8 * pp + 4)];
      #pragma unroll
      for (int bb = 0; bb < 4; ++bb) {
        float pv = w0.x * xs[bb][0];
        pv = __builtin_fmaf(w0.y, xs[bb][1], pv);
        pv = __builtin_fmaf(w0.z, xs[bb][2], pv);
        pv = __builtin_fmaf(w0.w, xs[bb][3], pv);
        pv = __builtin_fmaf(w1.x, xs[bb][4], pv);
        pv = __builtin_fmaf(w1.y, xs[bb][5], pv);
        pv = __builtin_fmaf(w1.z, xs[bb][6], pv);
        pv = __builtin_fmaf(w1.w, xs[bb][7], pv);
        if (MODE == 0) {
          s_r[bb][pp] += pv;
        } else {
          pr[bb][pp] = pv;
          acc[bb] = __builtin_fmaf(pv, vv[bb][pp], acc[bb]);
        }
      }
    }

    if (MODE != 0) {
      #pragma unroll
      for (int bb = 0; bb < 4; ++bb) {
        // full logit = both p-halves (quad_perm xor1 pairs lanes 2o/2o+1)
        const float full = dpp_add<0xB1>(acc[bb]);
        const float e = __expf(full);
        // sum over all 64 lanes = 2*Z[b] (each o counted twice via ph)
        float srow = e;
        srow = dpp_add<0x121>(srow);
        srow = dpp_add<0x122>(srow);
        srow = dpp_add<0x124>(srow);
        srow = dpp_add<0x128>(srow);
        float t2 = srow + __shfl_xor(srow, 16);
        const float S = t2 + __shfl_xor(t2, 32);   // = 2*Z
        const float rw = (2.0f * e) / S;           // e/Z
        #pragma unroll
        for (int pp = 0; pp < 8; ++pp)
          s_r[bb][pp] = __builtin_fmaf(rw, pr[bb][pp], s_r[bb][pp]);
        if (MODE == 2) {
          if (ph == 0)
            rw_out[((size_t)(wu * 4 + bb) * N_ + n) * O_ + o] = rw;
        }
      }
    }

    // buffer swap: all waves done reading w_lds[nn]; write W[n+1]; publish.
    if (nn + 1 < CHUNK_) {
      __syncthreads();
      *(float4*)&w_lds[swoff] = wreg;   // compiler inserts vmcnt wait for wreg
      __syncthreads();
    }
  }

  // epilogue, spart layout [blk][b][h][lane][4]: flat = blk*M_ + b*512 +
  // h*256 + lane*4 + j -> each float4 store = base + lane*16B, contiguous 1KB.
  if (ATOMIC) {
    #pragma unroll
    for (int bb = 0; bb < 4; ++bb) {
      #pragma unroll
      for (int h = 0; h < 2; ++h)
        #pragma unroll
        for (int j = 0; j < 4; ++j)
          atomicAdd(&s_out[(size_t)(wu * 4 + bb) * 512 + h * 256 + lane * 4 + j],
                    s_r[bb][h * 4 + j]);
    }
  } else {
    #pragma unroll
    for (int bb = 0; bb < 4; ++bb) {
      float* sp = s_out + (size_t)blockIdx.x * M_ + (size_t)(wu * 4 + bb) * 512 +
                  lane * 4;
      float4 st0, st1;
      st0.x = s_r[bb][0]; st0.y = s_r[bb][1]; st0.z = s_r[bb][2]; st0.w = s_r[bb][3];
      st1.x = s_r[bb][4]; st1.y = s_r[bb][5]; st1.z = s_r[bb][6]; st1.w = s_r[bb][7];
      *(float4*)sp = st0;
      *(float4*)(sp + 256) = st1;
    }
  }
}

// stage-1 reduction: P[K][M_] -> P2[16][M_]; grid 16 groups x 16 m-chunks.
// (element-wise over flat M_, layout-agnostic)
__global__ __launch_bounds__(1024)
void reduce1(const float* __restrict__ spart, float* __restrict__ p2, int K) {
  const int g  = blockIdx.x >> 4;
  const int mc = blockIdx.x & 15;
  const int kpg = K >> 4;
  const int m0 = mc * 2048 + threadIdx.x;
  float a0 = 0.0f, a1 = 0.0f;
  const float* p = spart + (size_t)(g * kpg) * M_;
  for (int k = 0; k < kpg; ++k) {
    a0 += p[(size_t)k * M_ + m0];
    a1 += p[(size_t)k * M_ + m0 + 1024];
  }
  p2[(size_t)g * M_ + m0]        = a0;
  p2[(size_t)g * M_ + m0 + 1024] = a1;
}

// sum ngroups (stride M_) + squash; optional v_add / zero_buf.
// src group layout from fused_pass: idx(b,o,p) = b*512 + ((p>>2)&1)*256 +
// (2*o + (p>>3))*4 + (p&3).
__global__ __launch_bounds__(1024)
void v_kernel(const float* __restrict__ src, int ngroups, float scale,
              const float* __restrict__ v_add, float* __restrict__ v_out,
              float* __restrict__ zero_buf) {
  __shared__ float sq[P_ * 65];
  const int t = threadIdx.x;
  const int p = t & 15;
  const int b = t >> 4;
  const int o = blockIdx.x;
  const int q = o * P_ + p;
  const int idx_src = b * 512 + ((p >> 2) & 1) * 256 + (2 * o + (p >> 3)) * 4 +
                      (p & 3);
  float acc = 0.0f;
  for (int g = 0; g < ngroups; ++g)
    acc += src[(size_t)g * M_ + idx_src];
  acc *= scale;
  sq[p * 65 + b] = acc * acc;
  if (zero_buf) zero_buf[blockIdx.x * 1024 + t] = 0.0f;
  __syncthreads();
  float s2 = 0.0f;
  #pragma unroll
  for (int pp = 0; pp < P_; ++pp) s2 += sq[pp * 65 + b];
  float sc = (s2 / (1.0f + s2)) / sqrtf(s2 + 1e-7f);
  float v = acc * sc;
  const int idx = b * OP_ + q;   // v layout [b][o][p]
  v_out[idx] = v + (v_add ? v_add[idx] : 0.0f);
}

extern "C" void kernel_launch(void* const* d_in, const int* in_sizes, int n_in,
                              void* d_out, int out_size, void* d_ws, size_t ws_size,
                              hipStream_t stream) {
  (void)in_sizes; (void)n_in; (void)out_size;
  const float* x = (const float*)d_in[0];
  const float* W = (const float*)d_in[1];
  float* out_v  = (float*)d_out;                       // [64][32][16]
  float* out_rw = out_v + (size_t)B_ * O_ * P_;        // [64][2048][32]
  float* vws   = (float*)d_ws;                         // v0
  float* vsum  = vws + M_;                             // v0+v1
  float* p2    = vsum + M_;                            // 16 * M_
  float* spart = p2 + 16 * M_;                         // NBLK_ * M_

  const size_t need = (size_t)(2 * M_ + 16 * M_ + (size_t)NBLK_ * M_) * 4;

  dim3 gF(NBLK_), bF(1024), gV(O_), bV(1024), gR(256);
  if (ws_size >= need) {
    fused_pass<0, false><<<gF, bF, 0, stream>>>(x, W, nullptr, spart, nullptr);
    reduce1<<<gR, bF, 0, stream>>>(spart, p2, NBLK_);
    v_kernel<<<gV, bV, 0, stream>>>(p2, 16, 1.0f / 32.0f, nullptr, vws, nullptr);
    fused_pass<1, false><<<gF, bF, 0, stream>>>(x, W, vws, spart, nullptr);
    reduce1<<<gR, bF, 0, stream>>>(spart, p2, NBLK_);
    v_kernel<<<gV, bV, 0, stream>>>(p2, 16, 1.0f, vws, vsum, nullptr);
    fused_pass<2, false><<<gF, bF, 0, stream>>>(x, W, vsum, spart, out_rw);
    reduce1<<<gR, bF, 0, stream>>>(spart, p2, NBLK_);
    v_kernel<<<gV, bV, 0, stream>>>(p2, 16, 1.0f, nullptr, out_v, nullptr);
  } else {
    // atomic fallback for small ws
    float* sAb = p2;
    float* sBb = sAb + M_;
    hipMemsetAsync(sAb, 0, (size_t)M_ * sizeof(float), stream);
    fused_pass<0, true><<<gF, bF, 0, stream>>>(x, W, nullptr, sAb, nullptr);
    v_kernel<<<gV, bV, 0, stream>>>(sAb, 1, 1.0f / 32.0f, nullptr, vws, sBb);
    fused_pass<1, true><<<gF, bF, 0, stream>>>(x, W, vws, sBb, nullptr);
    v_kernel<<<gV, bV, 0, stream>>>(sBb, 1, 1.0f, vws, vsum, sAb);
    fused_pass<2, true><<<gF, bF, 0, stream>>>(x, W, vsum, sAb, out_rw);
    v_kernel<<<gV, bV, 0, stream>>>(sAb, 1, 1.0f, nullptr, out_v, nullptr);
  }
}

// Round 4
// 224.641 us; speedup vs baseline: 1.2128x; 1.2103x over previous
//
#include <hip/hip_runtime.h>

static constexpr int B_    = 64;
static constexpr int N_    = 2048;
static constexpr int DI_   = 8;
static constexpr int O_    = 32;
static constexpr int P_    = 16;
static constexpr int OP_   = O_ * P_;      // 512
static constexpr int M_    = OP_ * B_;     // 32768 s elements
static constexpr int CHUNK_ = 8;
static constexpr int NBLK_  = N_ / CHUNK_; // 256 n-chunks
static constexpr int WSLICE_ = O_ * P_ * DI_;  // 4096 floats per n

// DPP add helper: v + dpp_mov(v). CTRL compile-time (0xB1 quad_perm[1,0,3,2];
// 0x121/2/4/8 = row_ror 1/2/4/8).
template <int CTRL>
__device__ __forceinline__ float dpp_add(float v) {
  int t = __builtin_amdgcn_update_dpp(0, __float_as_int(v), CTRL, 0xf, 0xf, false);
  return v + __int_as_float(t);
}

__device__ __forceinline__ float rfl(float v) {
  return __int_as_float(__builtin_amdgcn_readfirstlane(__float_as_int(v)));
}

// R4: R2/R3's fetch/write bomb was REGISTER SPILL to scratch (R2 and R3 had
// identical ~240MB fetch with different staging paths; common factor = ~130-160
// live floats vs the 64-VGPR cap that __launch_bounds__(1024,4) imposes;
// scratch working set 20MB/XCD >> 4MB L2 -> HBM). Fix = pressure engineering:
//  - 512-thread blocks, __launch_bounds__(512,2): 2 blocks/CU = 16 waves/CU
//    (same occupancy as before) but a 128-VGPR cap. Grid 512: block covers a
//    b-half (bh) x n-chunk (cn); spart layout unchanged ([cn][b][512] since
//    b = bh*32 + b_local).
//  - peak-window split: pp-loop computes pr[] only; v is loaded per-bb in a
//    SEPARATE dot pass afterwards (8 regs transient, not 32 persistent).
//    Peak live ~= s_r(32)+pr(32)+W(~16)+wreg(8)+addr(~10) ~= 100 < 128.
//  - x stays SGPR via readfirstlane (wave-uniform rows).
// Unchanged verified machinery: (o,ph) lane remap, LDS-internal XOR swizzle
// (linear coalesced global load -> ds_write to chunk tid^((tid>>4)&7); read
// addr (lane*64+(lane&7)*4)^(8pp)), in-wave DPP softmax, coalesced epilogue.
template <int MODE, bool ATOMIC>
__global__ __launch_bounds__(512, 2)
void fused_pass(const float* __restrict__ x, const float* __restrict__ W,
                const float* __restrict__ v_in, float* __restrict__ s_out,
                float* __restrict__ rw_out) {
  __shared__ __align__(16) float w_lds[WSLICE_];      // 16 KB, single buffer
  const int tid  = threadIdx.x;
  const int lane = tid & 63;
  const int wu   = __builtin_amdgcn_readfirstlane(tid >> 6);  // 0..7
  const int o    = lane >> 1;   // 0..31 output capsule
  const int ph   = lane & 1;    // p-half: p = ph*8 + pp
  const int cn   = blockIdx.x >> 1;      // n-chunk
  const int bh   = blockIdx.x & 1;       // b-half
  const int n0   = cn * CHUNK_;
  const int b0   = bh * 32 + wu * 4;     // wave's first b (wave-uniform)

  // staging: thread loads W chunks tid and tid+512 (linear, coalesced),
  // ds_writes to swizzled phys chunks (LDS-internal swizzle only).
  const int t2  = tid + 512;
  const int sw0 = (tid ^ ((tid >> 4) & 7)) * 4;
  const int sw1 = (t2  ^ ((t2  >> 4) & 7)) * 4;   // same key: +512 keeps bits 4-6
  // swizzled read base (floats): per-chunk addr = wbase ^ (8pp)
  const int wbase = lane * 64 + (lane & 7) * 4;

  float s_r[4][8];
  #pragma unroll
  for (int bb = 0; bb < 4; ++bb)
    #pragma unroll
    for (int pp = 0; pp < 8; ++pp) s_r[bb][pp] = 0.0f;

  // prologue: stage W[n0]
  {
    const float4 a = *(const float4*)(W + (size_t)n0 * WSLICE_ + tid * 4);
    const float4 b = *(const float4*)(W + (size_t)n0 * WSLICE_ + t2 * 4);
    *(float4*)&w_lds[sw0] = a;
    *(float4*)&w_lds[sw1] = b;
  }
  __syncthreads();

  #pragma unroll 1
  for (int nn = 0; nn < CHUNK_; ++nn) {
    const int n = n0 + nn;

    // prefetch W[n+1] into regs (linear, coalesced); consumed after compute.
    float4 wrA, wrB;
    if (nn + 1 < CHUNK_) {
      wrA = *(const float4*)(W + (size_t)(n + 1) * WSLICE_ + tid * 4);
      wrB = *(const float4*)(W + (size_t)(n + 1) * WSLICE_ + t2 * 4);
    }

    // x: wave-uniform 8 floats per b -> SGPRs via readfirstlane
    float xs[4][8];
    #pragma unroll
    for (int bb = 0; bb < 4; ++bb) {
      const float* xp = x + (size_t)(b0 + bb) * (N_ * DI_) + (size_t)n * DI_;
      const float4 xa = *(const float4*)xp;
      const float4 xc = *(const float4*)(xp + 4);
      xs[bb][0] = rfl(xa.x); xs[bb][1] = rfl(xa.y);
      xs[bb][2] = rfl(xa.z); xs[bb][3] = rfl(xa.w);
      xs[bb][4] = rfl(xc.x); xs[bb][5] = rfl(xc.y);
      xs[bb][6] = rfl(xc.z); xs[bb][7] = rfl(xc.w);
    }

    // pass 1: predictions only (no v live here -> low register peak)
    float pr[4][8];
    #pragma unroll
    for (int pp = 0; pp < 8; ++pp) {
      const float4 w0 = *(const float4*)&w_lds[wbase ^ (8 * pp)];
      const float4 w1 = *(const float4*)&w_lds[wbase ^ (8 * pp + 4)];
      #pragma unroll
      for (int bb = 0; bb < 4; ++bb) {
        float pv = w0.x * xs[bb][0];
        pv = __builtin_fmaf(w0.y, xs[bb][1], pv);
        pv = __builtin_fmaf(w0.z, xs[bb][2], pv);
        pv = __builtin_fmaf(w0.w, xs[bb][3], pv);
        pv = __builtin_fmaf(w1.x, xs[bb][4], pv);
        pv = __builtin_fmaf(w1.y, xs[bb][5], pv);
        pv = __builtin_fmaf(w1.z, xs[bb][6], pv);
        pv = __builtin_fmaf(w1.w, xs[bb][7], pv);
        if (MODE == 0) s_r[bb][pp] += pv;
        else           pr[bb][pp] = pv;
      }
    }

    // pass 2 (MODE!=0): per-bb v-dot (v transient: 8 regs), softmax, accumulate
    if (MODE != 0) {
      #pragma unroll
      for (int bb = 0; bb < 4; ++bb) {
        const float4* vp = (const float4*)(v_in + (size_t)(b0 + bb) * OP_ +
                                           o * P_ + ph * 8);
        const float4 va = vp[0];
        const float4 vc = vp[1];
        float acc = pr[bb][0] * va.x;
        acc = __builtin_fmaf(pr[bb][1], va.y, acc);
        acc = __builtin_fmaf(pr[bb][2], va.z, acc);
        acc = __builtin_fmaf(pr[bb][3], va.w, acc);
        acc = __builtin_fmaf(pr[bb][4], vc.x, acc);
        acc = __builtin_fmaf(pr[bb][5], vc.y, acc);
        acc = __builtin_fmaf(pr[bb][6], vc.z, acc);
        acc = __builtin_fmaf(pr[bb][7], vc.w, acc);
        // full logit = both p-halves (quad_perm xor1 pairs lanes 2o/2o+1)
        const float full = dpp_add<0xB1>(acc);
        const float e = __expf(full);
        // sum over all 64 lanes = 2*Z[b] (each o counted twice via ph)
        float srow = e;
        srow = dpp_add<0x121>(srow);
        srow = dpp_add<0x122>(srow);
        srow = dpp_add<0x124>(srow);
        srow = dpp_add<0x128>(srow);
        float t16 = srow + __shfl_xor(srow, 16);
        const float S = t16 + __shfl_xor(t16, 32);   // = 2*Z
        const float rw = (2.0f * e) / S;             // e/Z
        #pragma unroll
        for (int pp = 0; pp < 8; ++pp)
          s_r[bb][pp] = __builtin_fmaf(rw, pr[bb][pp], s_r[bb][pp]);
        if (MODE == 2) {
          if (ph == 0)
            rw_out[((size_t)(b0 + bb) * N_ + n) * O_ + o] = rw;
        }
      }
    }

    // buffer swap: all waves done reading w_lds[nn]; publish W[n+1].
    if (nn + 1 < CHUNK_) {
      __syncthreads();
      *(float4*)&w_lds[sw0] = wrA;   // compiler inserts vmcnt wait for wrA/B
      *(float4*)&w_lds[sw1] = wrB;
      __syncthreads();
    }
  }

  // epilogue, spart layout [cn][b][h][lane][4]: each float4 store is
  // base + lane*16B -> contiguous 1KB per instr.
  if (ATOMIC) {
    #pragma unroll
    for (int bb = 0; bb < 4; ++bb) {
      #pragma unroll
      for (int h = 0; h < 2; ++h)
        #pragma unroll
        for (int j = 0; j < 4; ++j)
          atomicAdd(&s_out[(size_t)(b0 + bb) * 512 + h * 256 + lane * 4 + j],
                    s_r[bb][h * 4 + j]);
    }
  } else {
    #pragma unroll
    for (int bb = 0; bb < 4; ++bb) {
      float* sp = s_out + (size_t)cn * M_ + (size_t)(b0 + bb) * 512 + lane * 4;
      float4 st0, st1;
      st0.x = s_r[bb][0]; st0.y = s_r[bb][1]; st0.z = s_r[bb][2]; st0.w = s_r[bb][3];
      st1.x = s_r[bb][4]; st1.y = s_r[bb][5]; st1.z = s_r[bb][6]; st1.w = s_r[bb][7];
      *(float4*)sp = st0;
      *(float4*)(sp + 256) = st1;
    }
  }
}

// stage-1 reduction: P[K][M_] -> P2[16][M_]; grid 16 groups x 16 m-chunks.
// (element-wise over flat M_, layout-agnostic)
__global__ __launch_bounds__(1024)
void reduce1(const float* __restrict__ spart, float* __restrict__ p2, int K) {
  const int g  = blockIdx.x >> 4;
  const int mc = blockIdx.x & 15;
  const int kpg = K >> 4;
  const int m0 = mc * 2048 + threadIdx.x;
  float a0 = 0.0f, a1 = 0.0f;
  const float* p = spart + (size_t)(g * kpg) * M_;
  for (int k = 0; k < kpg; ++k) {
    a0 += p[(size_t)k * M_ + m0];
    a1 += p[(size_t)k * M_ + m0 + 1024];
  }
  p2[(size_t)g * M_ + m0]        = a0;
  p2[(size_t)g * M_ + m0 + 1024] = a1;
}

// sum ngroups (stride M_) + squash; optional v_add / zero_buf.
// src group layout from fused_pass: idx(b,o,p) = b*512 + ((p>>2)&1)*256 +
// (2*o + (p>>3))*4 + (p&3).
__global__ __launch_bounds__(1024)
void v_kernel(const float* __restrict__ src, int ngroups, float scale,
              const float* __restrict__ v_add, float* __restrict__ v_out,
              float* __restrict__ zero_buf) {
  __shared__ float sq[P_ * 65];
  const int t = threadIdx.x;
  const int p = t & 15;
  const int b = t >> 4;
  const int o = blockIdx.x;
  const int q = o * P_ + p;
  const int idx_src = b * 512 + ((p >> 2) & 1) * 256 + (2 * o + (p >> 3)) * 4 +
                      (p & 3);
  float acc = 0.0f;
  for (int g = 0; g < ngroups; ++g)
    acc += src[(size_t)g * M_ + idx_src];
  acc *= scale;
  sq[p * 65 + b] = acc * acc;
  if (zero_buf) zero_buf[blockIdx.x * 1024 + t] = 0.0f;
  __syncthreads();
  float s2 = 0.0f;
  #pragma unroll
  for (int pp = 0; pp < P_; ++pp) s2 += sq[pp * 65 + b];
  float sc = (s2 / (1.0f + s2)) / sqrtf(s2 + 1e-7f);
  float v = acc * sc;
  const int idx = b * OP_ + q;   // v layout [b][o][p]
  v_out[idx] = v + (v_add ? v_add[idx] : 0.0f);
}

extern "C" void kernel_launch(void* const* d_in, const int* in_sizes, int n_in,
                              void* d_out, int out_size, void* d_ws, size_t ws_size,
                              hipStream_t stream) {
  (void)in_sizes; (void)n_in; (void)out_size;
  const float* x = (const float*)d_in[0];
  const float* W = (const float*)d_in[1];
  float* out_v  = (float*)d_out;                       // [64][32][16]
  float* out_rw = out_v + (size_t)B_ * O_ * P_;        // [64][2048][32]
  float* vws   = (float*)d_ws;                         // v0
  float* vsum  = vws + M_;                             // v0+v1
  float* p2    = vsum + M_;                            // 16 * M_
  float* spart = p2 + 16 * M_;                         // NBLK_ * M_

  const size_t need = (size_t)(2 * M_ + 16 * M_ + (size_t)NBLK_ * M_) * 4;

  dim3 gF(2 * NBLK_), bF(512), gV(O_), bV(1024), gR(256), bR(1024);
  if (ws_size >= need) {
    fused_pass<0, false><<<gF, bF, 0, stream>>>(x, W, nullptr, spart, nullptr);
    reduce1<<<gR, bR, 0, stream>>>(spart, p2, NBLK_);
    v_kernel<<<gV, bV, 0, stream>>>(p2, 16, 1.0f / 32.0f, nullptr, vws, nullptr);
    fused_pass<1, false><<<gF, bF, 0, stream>>>(x, W, vws, spart, nullptr);
    reduce1<<<gR, bR, 0, stream>>>(spart, p2, NBLK_);
    v_kernel<<<gV, bV, 0, stream>>>(p2, 16, 1.0f, vws, vsum, nullptr);
    fused_pass<2, false><<<gF, bF, 0, stream>>>(x, W, vsum, spart, out_rw);
    reduce1<<<gR, bR, 0, stream>>>(spart, p2, NBLK_);
    v_kernel<<<gV, bV, 0, stream>>>(p2, 16, 1.0f, nullptr, out_v, nullptr);
  } else {
    // atomic fallback for small ws
    float* sAb = p2;
    float* sBb = sAb + M_;
    hipMemsetAsync(sAb, 0, (size_t)M_ * sizeof(float), stream);
    fused_pass<0, true><<<gF, bF, 0, stream>>>(x, W, nullptr, sAb, nullptr);
    v_kernel<<<gV, bV, 0, stream>>>(sAb, 1, 1.0f / 32.0f, nullptr, vws, sBb);
    fused_pass<1, true><<<gF, bF, 0, stream>>>(x, W, vws, sBb, nullptr);
    v_kernel<<<gV, bV, 0, stream>>>(sBb, 1, 1.0f, vws, vsum, sAb);
    fused_pass<2, true><<<gF, bF, 0, stream>>>(x, W, vsum, sAb, out_rw);
    v_kernel<<<gV, bV, 0, stream>>>(sAb, 1, 1.0f, nullptr, out_v, nullptr);
  }
}